// Round 12
// baseline (177.940 us; speedup 1.0000x reference)
//
#include <hip/hip_runtime.h>
#include <stdint.h>

// DynamicSparseLinearAttention on MI355X.
// N=4, L=8192, H=8, D=V=128. Layout [n][l][h][d], row stride H*D = 1024 floats.
//
// Lessons: (R4) atomics write through L2 -> never. (R5) small grids starve the
// chip. (R6) per-lane strided 16B loads thrash L2; LDS staging with coalesced
// reads is mandatory. (R8) scalar LDS transpose reads cap at 2.4TB/s -> stage
// transposed+bf16-packed, frag reads = ds_read_b128. (R9-R11) ILP pipelining
// (2-deep prefetch, dbuf, lgkm-only barriers) is NULL at 2 blocks/CU: barrier
// lockstep + too few barrier domains. TLP is what works on this chip ->
// 1024 blocks x 256 thr, 4 resident blocks/CU, single-buffer LDS.
//
// 3 launches:
//  kv_vh:    fused retile+GEMM. Grid (CH=16, 8h, 4n x 2vhalf) = 1024 blocks x
//            256 thr (4 waves = 2 wr(d64) x 2 wc(v32)). Per 32-s step: stage
//            K[32s x 128d] (featmap, bf16-packed, transposed, b128 writes) and
//            V[32s x 64v-half] into 15.4KB LDS; frag reads = ds_read_b128;
//            8 MFMA + 4 ksum-MFMA. K staged by both vh blocks (L2-served).
//            Private fp32 partials, disjoint v-slabs, write-once. No atomics.
//  kv_merge: sum CH partials -> kvb bf16 [nh][v][d] + ksumg.
//  attn_out: Q staged to LDS bf16 (row*17 padded chunks), score during staging
//            (fp32 + shfl_xor), B-frags direct from L2-hot kvb. One barrier.

#define LSEQ 8192
#define NHD  1024   // H*D
#define SP   20     // LDS dwords per row: 16 s-pair slots + 4 pad

typedef __attribute__((ext_vector_type(4))) float f32x4;
typedef __attribute__((ext_vector_type(8))) short bf16x8;
typedef unsigned short ushort_t;

static __device__ __forceinline__ unsigned short f2bf(float x) {
  union { float f; uint32_t u; } v; v.f = x;
  uint32_t r = v.u + 0x7FFFu + ((v.u >> 16) & 1u);  // RNE
  return (unsigned short)(r >> 16);
}
static __device__ __forceinline__ uint32_t pack_bf(float a, float b) {
  return (uint32_t)f2bf(a) | ((uint32_t)f2bf(b) << 16);
}
static __device__ __forceinline__ float featmap(float x) {
  // elu(x)+1 = x+1 (x>0) else exp(x)
  return x > 0.f ? x + 1.f : __expf(x);
}

// LDS-only barrier (ds ops drained; global loads stay in flight).
#define BAR_LGKM() asm volatile("s_waitcnt lgkmcnt(0)\n\ts_barrier" ::: "memory")

// ---------------- Phase 1: fused retile + KV GEMM, v-half blocks ------------
// Grid (CH, 8 h, 8 = n*2+vh), 256 thr = 4 waves = wr(w>>1: d64) x wc(w&1: v32).
__global__ __launch_bounds__(256, 4) void kv_vh(const float* __restrict__ keys,
                                                const float* __restrict__ values,
                                                float* __restrict__ kvp,
                                                float* __restrict__ kspart) {
  __shared__ uint32_t kls[128 * SP];   // K: 128 d rows x 16 s-pair slots (+pad)
  __shared__ uint32_t vls[64 * SP];    // V: 64 v rows (this block's half)
  const int tid = threadIdx.x;
  const int chunk = blockIdx.x, CH = gridDim.x;
  const int h = blockIdx.y;
  const int n = blockIdx.z >> 1, vh = blockIdx.z & 1;
  const int nh = n * 8 + h;
  const int lane = tid & 63, w = tid >> 6;
  const int wr = w >> 1, wc = w & 1;
  const int lr = lane & 15, lg = lane >> 4;
  const int sPer = LSEQ / CH;        // 512 at CH=16
  const int steps = sPer / 32;

  const size_t gb = ((size_t)n * LSEQ + (size_t)chunk * sPer) * NHD + h * 128;
  const float* gk = keys + gb;
  const float* gv = values + gb + vh * 64;

  // K staging: wave w owns s-rows 8w..8w+7; lane a owns d-pair (2a, 2a+1).
  const int a = lane;
  const int fswA = 4 * ((a >> 2) & 3);             // = 4*((d>>3)&3), d=2a,2a+1
  const int kslot = (4 * w) ^ fswA;                // b128 slot base (4 dwords)
  // V staging: lane: vloc = 2*(a&31) (+1); shalf = a>>5; rows s = 8w+4*shalf+j.
  const int vloc = 2 * (a & 31);
  const int shalf = a >> 5;
  const int fswV = 4 * ((vloc >> 3) & 3);
  const int vslot = (4 * w + 2 * shalf) ^ fswV;    // b64 slot base (2 dwords)

  f32x4 acc[4][2] = {};
  f32x4 ak[4] = {};
  bf16x8 ones;
  { uint32_t* u = (uint32_t*)&ones; u[0] = u[1] = u[2] = u[3] = 0x3F803F80u; }

#define ISSUE(T)                                                  \
  do {                                                            \
    _Pragma("unroll") for (int j = 0; j < 8; ++j)                 \
      kr[j] = *(const float2*)(gk + (size_t)((T) * 32 + 8 * w + j) * NHD + 2 * a); \
    _Pragma("unroll") for (int j = 0; j < 4; ++j)                 \
      vr[j] = *(const float2*)(gv + (size_t)((T) * 32 + 8 * w + 4 * shalf + j) * NHD + vloc); \
  } while (0)

  float2 kr[8], vr[4];
  ISSUE(0);

  for (int t = 0; t < steps; ++t) {
    // ---- stage regs -> LDS (featmap K, bf16 pack, transposed) ----
    {
      uint32_t k0[4], k1[4];
#pragma unroll
      for (int u = 0; u < 4; ++u) {
        k0[u] = pack_bf(featmap(kr[2 * u].x), featmap(kr[2 * u + 1].x));
        k1[u] = pack_bf(featmap(kr[2 * u].y), featmap(kr[2 * u + 1].y));
      }
      *(uint4*)&kls[(2 * a) * SP + kslot]     = make_uint4(k0[0], k0[1], k0[2], k0[3]);
      *(uint4*)&kls[(2 * a + 1) * SP + kslot] = make_uint4(k1[0], k1[1], k1[2], k1[3]);
      uint2 v0, v1;
      v0.x = pack_bf(vr[0].x, vr[1].x); v0.y = pack_bf(vr[2].x, vr[3].x);
      v1.x = pack_bf(vr[0].y, vr[1].y); v1.y = pack_bf(vr[2].y, vr[3].y);
      *(uint2*)&vls[vloc * SP + vslot]       = v0;
      *(uint2*)&vls[(vloc + 1) * SP + vslot] = v1;
    }
    BAR_LGKM();
    if (t + 1 < steps) ISSUE(t + 1);   // loads fly under MFMA + next barrier
    // ---- fragment reads (b128) + MFMA ----
    {
      bf16x8 af[4], bfr[2];
#pragma unroll
      for (int fr = 0; fr < 4; ++fr) {
        int d = wr * 64 + fr * 16 + lr;
        af[fr] = *(const bf16x8*)&kls[d * SP + ((4 * lg) ^ (4 * ((d >> 3) & 3)))];
      }
#pragma unroll
      for (int fc = 0; fc < 2; ++fc) {
        int v = wc * 32 + fc * 16 + lr;   // local v within the half
        bfr[fc] = *(const bf16x8*)&vls[v * SP + ((4 * lg) ^ (4 * ((v >> 3) & 3)))];
      }
#pragma unroll
      for (int fr = 0; fr < 4; ++fr)
#pragma unroll
        for (int fc = 0; fc < 2; ++fc)
          acc[fr][fc] = __builtin_amdgcn_mfma_f32_16x16x32_bf16(af[fr], bfr[fc], acc[fr][fc], 0, 0, 0);
      if (wc == 0 && vh == 0) {
#pragma unroll
        for (int fr = 0; fr < 4; ++fr)
          ak[fr] = __builtin_amdgcn_mfma_f32_16x16x32_bf16(af[fr], ones, ak[fr], 0, 0, 0);
      }
    }
    BAR_LGKM();
  }
#undef ISSUE

  // C/D: col(v)=lane&15, row(d)=(lane>>4)*4+j. Disjoint v-slab, write-once.
  float* dst = kvp + ((size_t)chunk * 32 + nh) * 16384;
#pragma unroll
  for (int fr = 0; fr < 4; ++fr)
#pragma unroll
    for (int fc = 0; fc < 2; ++fc) {
      int d0 = wr * 64 + fr * 16 + lg * 4;
      int v  = vh * 64 + wc * 32 + fc * 16 + lr;
      *(float4*)(dst + (size_t)v * 128 + d0) =
          make_float4(acc[fr][fc][0], acc[fr][fc][1], acc[fr][fc][2], acc[fr][fc][3]);
    }
  if (wc == 0 && vh == 0 && lr == 0) {
    float* ks = kspart + ((size_t)chunk * 32 + nh) * 128;
#pragma unroll
    for (int fr = 0; fr < 4; ++fr)
      *(float4*)(ks + wr * 64 + fr * 16 + lg * 4) =
          make_float4(ak[fr][0], ak[fr][1], ak[fr][2], ak[fr][3]);
  }
}

// ---------------- Phase 1c: merge partials ----------------
__global__ __launch_bounds__(256) void kv_merge(const float* __restrict__ kvp,
                                                const float* __restrict__ kspart,
                                                ushort_t* __restrict__ kvb,
                                                float* __restrict__ ksumg,
                                                int CH) {
  const int nh = blockIdx.x, q = blockIdx.y, tid = threadIdx.x;
  const size_t off = (size_t)nh * 16384 + q * 4096;
#pragma unroll
  for (int i = 0; i < 4; ++i) {
    size_t idx = off + (size_t)(i * 256 + tid) * 4;
    f32x4 s = {};
    for (int c = 0; c < CH; ++c)
      s += *(const f32x4*)(kvp + (size_t)c * 524288 + idx);
    *(uint2*)(kvb + idx) = make_uint2(pack_bf(s[0], s[1]), pack_bf(s[2], s[3]));
  }
  if (q == 0 && tid < 128) {
    float s = 0.f;
    for (int c = 0; c < CH; ++c) s += kspart[((size_t)c * 32 + nh) * 128 + tid];
    ksumg[nh * 128 + tid] = s;
  }
}

// ---------------- Phase 2: LDS-staged Q + direct-global B ----------------
__global__ __launch_bounds__(256, 4) void attn_out(const float* __restrict__ q,
                                                   const ushort_t* __restrict__ kvb,
                                                   const float* __restrict__ ksumg,
                                                   const float* __restrict__ thrp,
                                                   float* __restrict__ out) {
  __shared__ __align__(16) uint32_t As[128 * 17 * 4];  // 34.8KB
  __shared__ float zrow[128];

  const int tid = threadIdx.x;
  const int mc = blockIdx.x, nh = blockIdx.y;
  const int n = nh >> 3, h = nh & 7;
  const size_t qoff = ((size_t)(n * LSEQ + mc * 128)) * NHD + h * 128;
  const float thr = thrp[0];

  const int c4 = tid & 31;
  const float4 kk = *(const float4*)(ksumg + nh * 128 + c4 * 4);

  // ---- stage Qf -> As (bf16) + fp32 score on the fly ----
#pragma unroll
  for (int it = 0; it < 16; ++it) {
    int rr = it * 8 + (tid >> 5);
    float4 qv = *(const float4*)(q + qoff + (size_t)rr * NHD + c4 * 4);
    float f0 = featmap(qv.x), f1 = featmap(qv.y), f2 = featmap(qv.z), f3 = featmap(qv.w);
    uint32_t* dst = &As[(rr * 17 + (c4 >> 1)) * 4 + (c4 & 1) * 2];
    dst[0] = pack_bf(f0, f1);
    dst[1] = pack_bf(f2, f3);
    float p = f0 * kk.x + f1 * kk.y + f2 * kk.z + f3 * kk.w;
    p += __shfl_xor(p, 1);  p += __shfl_xor(p, 2);  p += __shfl_xor(p, 4);
    p += __shfl_xor(p, 8);  p += __shfl_xor(p, 16);
    if (c4 == 0) {
      float sp = p > thr ? p : 0.f;
      zrow[rr] = 1.f / (sp + 1e-6f);
    }
  }
  __syncthreads();

  // ---- MFMA: A from LDS, B direct from kvb (L2-hot 32KB) ----
  const int lane = tid & 63;
  const int w = tid >> 6;
  const int lr = lane & 15, lg = lane >> 4;
  const ushort_t* kvp = kvb + (size_t)nh * 16384;   // [v][d] bf16

  f32x4 acc0[8] = {};
  f32x4 acc1[8] = {};
#pragma unroll
  for (int ks = 0; ks < 4; ++ks) {
    const int c8 = ks * 4 + lg;
    const int dof = ks * 32 + lg * 8;
    const int r0 = w * 32 + lr;
    bf16x8 a0 = *(const bf16x8*)&As[(r0 * 17 + c8) * 4];
    bf16x8 a1 = *(const bf16x8*)&As[((r0 + 16) * 17 + c8) * 4];
#pragma unroll
    for (int ct = 0; ct < 8; ++ct) {
      bf16x8 bb = *(const bf16x8*)(kvp + (size_t)((ct * 16 + lr) * 128) + dof);
      acc0[ct] = __builtin_amdgcn_mfma_f32_16x16x32_bf16(a0, bb, acc0[ct], 0, 0, 0);
      acc1[ct] = __builtin_amdgcn_mfma_f32_16x16x32_bf16(a1, bb, acc1[ct], 0, 0, 0);
    }
  }

  float z0[4], z1[4];
#pragma unroll
  for (int j = 0; j < 4; ++j) {
    z0[j] = zrow[w * 32 + lg * 4 + j];
    z1[j] = zrow[w * 32 + 16 + lg * 4 + j];
  }
  float* op = out + qoff;
#pragma unroll
  for (int ct = 0; ct < 8; ++ct)
#pragma unroll
    for (int jj = 0; jj < 4; ++jj) {
      int row = w * 32 + lg * 4 + jj;   // C/D: col=lane&15, row=(lane>>4)*4+jj
      op[(size_t)row * NHD + ct * 16 + lr]        = acc0[ct][jj] * z0[jj];
      op[(size_t)(row + 16) * NHD + ct * 16 + lr] = acc1[ct][jj] * z1[jj];
    }
}

extern "C" void kernel_launch(void* const* d_in, const int* in_sizes, int n_in,
                              void* d_out, int out_size, void* d_ws, size_t ws_size,
                              hipStream_t stream) {
  const float* queries   = (const float*)d_in[0];
  const float* keys      = (const float*)d_in[1];
  const float* values    = (const float*)d_in[2];
  const float* threshold = (const float*)d_in[3];
  float* out = (float*)d_out;

  // ws: kvp CH*2MB | kspart CH*16KB | kvb 1MB | ksumg 16KB   (CH=16 -> ~34.9MB)
  int CH = 16;
  while (CH > 1 &&
         (size_t)CH * (524288 + 32 * 128) * 4 + (size_t)32 * 16384 * 2 + 32 * 128 * 4 > ws_size)
    CH >>= 1;
  float* kvp     = (float*)d_ws;
  float* kspart  = kvp + (size_t)CH * 524288;
  ushort_t* kvb  = (ushort_t*)(kspart + (size_t)CH * 32 * 128);
  float* ksumg   = (float*)(kvb + (size_t)32 * 16384);

  kv_vh<<<dim3(CH, 8, 8), 256, 0, stream>>>(keys, values, kvp, kspart);
  kv_merge<<<dim3(32, 4), 256, 0, stream>>>(kvp, kspart, kvb, ksumg, CH);
  attn_out<<<dim3(64, 32), 256, 0, stream>>>(queries, kvb, ksumg, threshold, out);
}